// Round 14
// baseline (344.260 us; speedup 1.0000x reference)
//
#include <hip/hip_runtime.h>
#include <stdint.h>

#define SEQ      1024
#define NT       128
#define NBATCH   256
#define MID      512
#define WS_STRIDE 132       // 128 floats + kSum

typedef float v2f __attribute__((ext_vector_type(2)));

// 16 NAMED v2f weight regs (f32 pairs, pre-unpacked) = 32 VGPRs.
// Total live ~58: inside the 64-reg occupancy band R13 proved holds.
#define RALL(X) X(0) X(1) X(2) X(3) X(4) X(5) X(6) X(7) \
                X(8) X(9) X(10) X(11) X(12) X(13) X(14) X(15)
#define DECLW(k) v2f W##k;
#define INITW(k) { \
    W##k.x = __expf(wbase[(2 * (k)    ) * wstr]); \
    W##k.y = __expf(wbase[(2 * (k) + 1) * wstr]); }
#define PINW(k)  asm volatile("" : "+v"(W##k));

// state u32 (bf16 pair) -> v2f, then one v_pk_fma_f32
#define UPK(u_) (v2f){ __uint_as_float((u_) << 16), __uint_as_float((u_) & 0xffff0000u) }
#define MQ(c, k0, k1, k2, k3) { \
    uint4 u_ = *(const uint4*)(gp + 4 * (c)); \
    a0 = __builtin_elementwise_fma(W##k0, UPK(u_.x), a0); \
    a1 = __builtin_elementwise_fma(W##k1, UPK(u_.y), a1); \
    a2 = __builtin_elementwise_fma(W##k2, UPK(u_.z), a2); \
    a3 = __builtin_elementwise_fma(W##k3, UPK(u_.w), a3); }

// 32-tag quarter dot + cross-q combine (partners = adjacent lanes)
#define MATVEC32(S_) { \
    v2f a0 = {0.f,0.f}, a1 = {0.f,0.f}, a2 = {0.f,0.f}, a3 = {0.f,0.f}; \
    MQ(0,0,1,2,3) MQ(1,4,5,6,7) MQ(2,8,9,10,11) MQ(3,12,13,14,15) \
    v2f at_ = (a0 + a1) + (a2 + a3); \
    S_ = at_.x + at_.y; \
    S_ += __shfl_xor(S_, 1, 64); \
    S_ += __shfl_xor(S_, 2, 64); }

#define BF16_STORE(buf_, val_) { \
    uint32_t pk_; \
    asm("v_cvt_pk_bf16_f32 %0, %1, %2" : "=v"(pk_) : "v"(val_), "v"(val_)); \
    ((unsigned short*)(buf_))[jt] = (unsigned short)(pk_ & 0xffffu); }

// blocks [0,256):    forward chains (batch = blk, steps 1..512)
// blocks [256,512):  backward chains (batch = blk-256, steps 1023..513)
// blocks [512,544):  score gathers (8 batches each)
__global__ __launch_bounds__(512) void crf_chains(
    const float* __restrict__ emissions,   // [B, SEQ, NT]
    const float* __restrict__ transitions, // [NT, NT]
    const int*   __restrict__ tags,        // [B, SEQ]
    const float* __restrict__ mask,        // [B, SEQ]
    float* __restrict__ out,               // [1]
    float* __restrict__ ws)                // [2*256*132]
{
    const int blk = blockIdx.x;
    const int tid = threadIdx.x;

    if (blk >= 2 * NBATCH) {
        // ---------------- score blocks ----------------
        int b    = (blk - 2 * NBATCH) * 8 + (tid >> 6);
        int lane = tid & 63;
        const float* emb = emissions + (size_t)b * SEQ * NT;
        const int*   tgb = tags + (size_t)b * SEQ;
        const float* mkb = mask + (size_t)b * SEQ;
        float sc = 0.f;
        for (int t = lane; t < SEQ; t += 64) {
            int   tg = tgb[t];
            float mt = mkb[t];
            sc += emb[t * NT + tg] * mt;
            if (t >= 1) sc += transitions[tgb[t - 1] * NT + tg] * mt;
        }
#pragma unroll
        for (int o = 32; o > 0; o >>= 1) sc += __shfl_down(sc, o, 64);
        if (lane == 0) atomicAdd(out, -sc * (1.0f / NBATCH));
        return;
    }

    // ---------------- chain block ----------------
    // state = 64 u32 bf16 pairs (tags 2i, 2i+1), double-buffered
    __shared__ __align__(16) uint32_t buf[2][NT / 2];

    const int jt = tid >> 2;   // owned output tag 0..127
    const int q  = tid & 3;    // predecessor quarter (32 tags)

    const bool fwd = (blk < NBATCH);
    const int  b   = fwd ? blk : blk - NBATCH;

    const float* emb = emissions + (size_t)b * SEQ * NT;
    const float* mkb = mask + (size_t)b * SEQ;

    // fwd: expT[32q+2k][jt] (col jt, stride NT); bwd: expT[jt][32q+2k] (row, contig)
    const float* wbase = fwd ? (transitions + (size_t)(32 * q) * NT + jt)
                             : (transitions + (size_t)jt * NT + 32 * q);
    const int    wstr  = fwd ? NT : 1;

    RALL(DECLW)
    RALL(INITW)
    RALL(PINW)

    int   kSum = 0, p = 0;
    float gcur = 0.f, beta = 1.0f;
    float E0, E1, M0, M1;

    if (fwd) {
        gcur = __expf(emb[jt]);
        if (q == 0) BF16_STORE(buf[0], gcur);
        E0 = emb[1 * NT + jt];  E1 = emb[2 * NT + jt];
        M0 = mkb[1];            M1 = mkb[2];
    } else {
        float w0 = __expf(emb[(size_t)(SEQ - 1) * NT + jt]);   // w_1023 (beta=1)
        if (q == 0) BF16_STORE(buf[0], w0);
        E0 = emb[(size_t)(SEQ - 2) * NT + jt];
        E1 = emb[(size_t)(SEQ - 3) * NT + jt];
        M0 = mkb[SEQ - 1];      M1 = mkb[SEQ - 2];
    }
    __syncthreads();

    if (fwd) {
        // ---------- forward: 512 steps, t = 1+s ----------
        for (int s = 0; s < MID; ++s) {
            float En = emb[(size_t)(3 + s) * NT + jt];   // <= 514
            float Mn = mkb[3 + s];
            if (M0 != 0.0f) {
                const uint32_t* gp = buf[p] + 16 * q;
                uint32_t anchor = buf[p][0];
                float sres;
                MATVEC32(sres);
                int   e  = (int)((anchor >> 7) & 0xff);  // bf16 exp of tag0
                float rc = __uint_as_float((uint32_t)(254 - e) << 23);
                kSum += e - 127;
                if (q == 0) {
                    gcur = sres * rc * __expf(E0);
                    BF16_STORE(buf[p ^ 1], gcur);
                }
                p ^= 1;
            }
            __syncthreads();
            E0 = E1; E1 = En; M0 = M1; M1 = Mn;
        }
        float* wsb = ws + (size_t)b * WS_STRIDE;
        if (q == 0)  wsb[jt] = gcur;          // alpha_512 (pow2-scaled)
        if (tid == 0) wsb[128] = (float)kSum;
    } else {
        // ---------- backward: 511 steps, t = 1023-s; buf holds w = beta.*expE ----------
        for (int s = 0; s < MID - 1; ++s) {
            float En = emb[(size_t)(SEQ - 4 - s) * NT + jt];  // >= 510
            float Mn = mkb[SEQ - 3 - s];
            {
                const uint32_t* gp = buf[p] + 16 * q;
                uint32_t anchor = buf[p][0];
                float sres;
                MATVEC32(sres);
                int   e  = (int)((anchor >> 7) & 0xff);
                float rc = __uint_as_float((uint32_t)(254 - e) << 23);
                kSum += e - 127;
                float bn = (M0 != 0.0f) ? sres * rc : beta * rc;
                beta = bn;
                if (q == 0) {
                    float g = bn * __expf(E0);   // w_{t-1}
                    BF16_STORE(buf[p ^ 1], g);
                }
                p ^= 1;
            }
            __syncthreads();
            E0 = E1; E1 = En; M0 = M1; M1 = Mn;
        }
        float* wsb = ws + (size_t)(NBATCH + b) * WS_STRIDE;
        if (q == 0)  wsb[jt] = beta;          // beta_512 (pow2-scaled)
        if (tid == 0) wsb[128] = (float)kSum;
    }
}

// Z = sum_i alpha_MID[i] * beta_MID[i] * 2^(kF+kB)
__global__ __launch_bounds__(64) void crf_combine(
    const float* __restrict__ ws, float* __restrict__ out)
{
    int b    = blockIdx.x;
    int lane = threadIdx.x;
    const float* af = ws + (size_t)b * WS_STRIDE;
    const float* bf = ws + (size_t)(NBATCH + b) * WS_STRIDE;
    float d = af[lane] * bf[lane] + af[lane + 64] * bf[lane + 64];
#pragma unroll
    for (int o = 32; o > 0; o >>= 1) d += __shfl_down(d, o, 64);
    if (lane == 0) {
        float logZ = __logf(d) + (af[128] + bf[128]) * 0.69314718055994531f;
        atomicAdd(out, logZ * (1.0f / NBATCH));
    }
}

extern "C" void kernel_launch(void* const* d_in, const int* in_sizes, int n_in,
                              void* d_out, int out_size, void* d_ws, size_t ws_size,
                              hipStream_t stream) {
    const float* emissions   = (const float*)d_in[0];
    const float* transitions = (const float*)d_in[1];
    const int*   tags        = (const int*)d_in[2];
    const float* mask        = (const float*)d_in[3];
    float*       out         = (float*)d_out;
    float*       ws          = (float*)d_ws;

    hipMemsetAsync(out, 0, sizeof(float), stream);
    crf_chains<<<2 * NBATCH + 32, 512, 0, stream>>>(
        emissions, transitions, tags, mask, out, ws);
    crf_combine<<<NBATCH, 64, 0, stream>>>(ws, out);
}

// Round 16
// 306.234 us; speedup vs baseline: 1.1242x; 1.1242x over previous
//
#include <hip/hip_runtime.h>
#include <stdint.h>

#define SEQ      1024
#define NT       128
#define NBATCH   256
#define MID      512
#define WS_STRIDE 132       // 128 floats + kSum
#define QS       36         // padded quarter stride (floats): q-groups on disjoint banks

// 16 NAMED u32 weight regs (bf16 pairs) = 16 VGPRs -> total live ~30, the
// R13-proven-resident configuration (f32 weights spill: R14; dot2 asm: R15 wrong).
#define RALL(X) X(0) X(1) X(2) X(3) X(4) X(5) X(6) X(7) \
                X(8) X(9) X(10) X(11) X(12) X(13) X(14) X(15)
#define DECLW(k) uint32_t W##k;
#define INITW(k) { \
    float f0_ = __expf(wbase[(2 * (k)    ) * wstr]); \
    float f1_ = __expf(wbase[(2 * (k) + 1) * wstr]); \
    asm("v_cvt_pk_bf16_f32 %0, %1, %2" : "=v"(W##k) : "v"(f0_), "v"(f1_)); }
#define PINW(k)  asm volatile("" : "+v"(W##k));

#define UPLO(u_) __uint_as_float((u_) << 16)
#define UPHI(u_) __uint_as_float((u_) & 0xffff0000u)

// f32 state: per pair = 2 weight-unpacks + 2 fmaf (4 ops, was 6 with packed state)
#define MQ(c, k0, k1) { \
    float4 s_ = *(const float4*)(gp + 4 * (c)); \
    a0 = fmaf(UPLO(W##k0), s_.x, a0); \
    a1 = fmaf(UPHI(W##k0), s_.y, a1); \
    a2 = fmaf(UPLO(W##k1), s_.z, a2); \
    a3 = fmaf(UPHI(W##k1), s_.w, a3); }

// 32-tag quarter dot + cross-q combine (partners = adjacent lanes)
#define MATVEC32(S_) { \
    float a0 = 0.f, a1 = 0.f, a2 = 0.f, a3 = 0.f; \
    MQ(0,0,1) MQ(1,2,3) MQ(2,4,5) MQ(3,6,7) \
    MQ(4,8,9) MQ(5,10,11) MQ(6,12,13) MQ(7,14,15) \
    S_ = (a0 + a1) + (a2 + a3); \
    S_ += __shfl_xor(S_, 1, 64); \
    S_ += __shfl_xor(S_, 2, 64); }

// tag j lives at padded offset QS*(j>>5) + (j&31)
#define TAGOFF(j_) (QS * ((j_) >> 5) + ((j_) & 31))

// blocks [0,256):    forward chains (batch = blk, steps 1..512)
// blocks [256,512):  backward chains (batch = blk-256, steps 1023..513)
// blocks [512,544):  score gathers (8 batches each)
__global__ __launch_bounds__(512) void crf_chains(
    const float* __restrict__ emissions,   // [B, SEQ, NT]
    const float* __restrict__ transitions, // [NT, NT]
    const int*   __restrict__ tags,        // [B, SEQ]
    const float* __restrict__ mask,        // [B, SEQ]
    float* __restrict__ out,               // [1]
    float* __restrict__ ws)                // [2*256*132]
{
    const int blk = blockIdx.x;
    const int tid = threadIdx.x;

    if (blk >= 2 * NBATCH) {
        // ---------------- score blocks ----------------
        int b    = (blk - 2 * NBATCH) * 8 + (tid >> 6);
        int lane = tid & 63;
        const float* emb = emissions + (size_t)b * SEQ * NT;
        const int*   tgb = tags + (size_t)b * SEQ;
        const float* mkb = mask + (size_t)b * SEQ;
        float sc = 0.f;
        for (int t = lane; t < SEQ; t += 64) {
            int   tg = tgb[t];
            float mt = mkb[t];
            sc += emb[t * NT + tg] * mt;
            if (t >= 1) sc += transitions[tgb[t - 1] * NT + tg] * mt;
        }
#pragma unroll
        for (int o = 32; o > 0; o >>= 1) sc += __shfl_down(sc, o, 64);
        if (lane == 0) atomicAdd(out, -sc * (1.0f / NBATCH));
        return;
    }

    // ---------------- chain block ----------------
    // state = 128 f32, quarters padded to QS floats, double-buffered
    __shared__ __align__(16) float buf[2][4 * QS];

    const int jt = tid >> 2;   // owned output tag 0..127
    const int q  = tid & 3;    // predecessor quarter (32 tags)

    const bool fwd = (blk < NBATCH);
    const int  b   = fwd ? blk : blk - NBATCH;

    const float* emb = emissions + (size_t)b * SEQ * NT;
    const float* mkb = mask + (size_t)b * SEQ;

    // fwd: expT[32q+2k][jt] (col jt, stride NT); bwd: expT[jt][32q+2k] (row, contig)
    const float* wbase = fwd ? (transitions + (size_t)(32 * q) * NT + jt)
                             : (transitions + (size_t)jt * NT + 32 * q);
    const int    wstr  = fwd ? NT : 1;

    RALL(DECLW)
    RALL(INITW)
    RALL(PINW)

    int   kSum = 0, p = 0;
    float gcur = 0.f, beta = 1.0f;
    float E0, E1, M0, M1;

    if (fwd) {
        gcur = __expf(emb[jt]);
        if (q == 0) buf[0][TAGOFF(jt)] = gcur;
        E0 = emb[1 * NT + jt];  E1 = emb[2 * NT + jt];
        M0 = mkb[1];            M1 = mkb[2];
    } else {
        float w0 = __expf(emb[(size_t)(SEQ - 1) * NT + jt]);   // w_1023 (beta=1)
        if (q == 0) buf[0][TAGOFF(jt)] = w0;
        E0 = emb[(size_t)(SEQ - 2) * NT + jt];
        E1 = emb[(size_t)(SEQ - 3) * NT + jt];
        M0 = mkb[SEQ - 1];      M1 = mkb[SEQ - 2];
    }
    __syncthreads();

    if (fwd) {
        // ---------- forward: 512 steps, t = 1+s ----------
        for (int s = 0; s < MID; ++s) {
            float En = emb[(size_t)(3 + s) * NT + jt];   // <= 514
            float Mn = mkb[3 + s];
            if (M0 != 0.0f) {
                const float* gp = buf[p] + QS * q;
                uint32_t abits = __float_as_uint(buf[p][0]);  // anchor tag0
                float sres;
                MATVEC32(sres);
                int   e  = (int)((abits >> 23) & 0xff);
                float rc = __uint_as_float((uint32_t)(254 - e) << 23);  // 2^-(e-127)
                kSum += e - 127;
                if (q == 0) {
                    gcur = sres * rc * __expf(E0);
                    buf[p ^ 1][TAGOFF(jt)] = gcur;
                }
                p ^= 1;
            }
            __syncthreads();
            E0 = E1; E1 = En; M0 = M1; M1 = Mn;
        }
        float* wsb = ws + (size_t)b * WS_STRIDE;
        if (q == 0)  wsb[jt] = gcur;          // alpha_512 (pow2-scaled)
        if (tid == 0) wsb[128] = (float)kSum;
    } else {
        // ---------- backward: 511 steps, t = 1023-s; buf holds w = beta.*expE ----------
        for (int s = 0; s < MID - 1; ++s) {
            float En = emb[(size_t)(SEQ - 4 - s) * NT + jt];  // >= 510
            float Mn = mkb[SEQ - 3 - s];
            {
                const float* gp = buf[p] + QS * q;
                uint32_t abits = __float_as_uint(buf[p][0]);
                float sres;
                MATVEC32(sres);
                int   e  = (int)((abits >> 23) & 0xff);
                float rc = __uint_as_float((uint32_t)(254 - e) << 23);
                kSum += e - 127;
                float bn = (M0 != 0.0f) ? sres * rc : beta * rc;
                beta = bn;
                if (q == 0) {
                    buf[p ^ 1][TAGOFF(jt)] = bn * __expf(E0);   // w_{t-1}
                }
                p ^= 1;
            }
            __syncthreads();
            E0 = E1; E1 = En; M0 = M1; M1 = Mn;
        }
        float* wsb = ws + (size_t)(NBATCH + b) * WS_STRIDE;
        if (q == 0)  wsb[jt] = beta;          // beta_512 (pow2-scaled)
        if (tid == 0) wsb[128] = (float)kSum;
    }
}

// Z = sum_i alpha_MID[i] * beta_MID[i] * 2^(kF+kB)
__global__ __launch_bounds__(64) void crf_combine(
    const float* __restrict__ ws, float* __restrict__ out)
{
    int b    = blockIdx.x;
    int lane = threadIdx.x;
    const float* af = ws + (size_t)b * WS_STRIDE;
    const float* bf = ws + (size_t)(NBATCH + b) * WS_STRIDE;
    float d = af[lane] * bf[lane] + af[lane + 64] * bf[lane + 64];
#pragma unroll
    for (int o = 32; o > 0; o >>= 1) d += __shfl_down(d, o, 64);
    if (lane == 0) {
        float logZ = __logf(d) + (af[128] + bf[128]) * 0.69314718055994531f;
        atomicAdd(out, logZ * (1.0f / NBATCH));
    }
}

extern "C" void kernel_launch(void* const* d_in, const int* in_sizes, int n_in,
                              void* d_out, int out_size, void* d_ws, size_t ws_size,
                              hipStream_t stream) {
    const float* emissions   = (const float*)d_in[0];
    const float* transitions = (const float*)d_in[1];
    const int*   tags        = (const int*)d_in[2];
    const float* mask        = (const float*)d_in[3];
    float*       out         = (float*)d_out;
    float*       ws          = (float*)d_ws;

    hipMemsetAsync(out, 0, sizeof(float), stream);
    crf_chains<<<2 * NBATCH + 32, 512, 0, stream>>>(
        emissions, transitions, tags, mask, out, ws);
    crf_combine<<<NBATCH, 64, 0, stream>>>(ws, out);
}